// Round 3
// baseline (879.585 us; speedup 1.0000x reference)
//
#include <hip/hip_runtime.h>
#include <hip/hip_bf16.h>

#define B 2
#define C 64
#define N 8192
#define K 16
#define CO 64
#define SEG 8
#define TM 64

// ---------------- kernel 1: per-point squared norms ----------------
__global__ __launch_bounds__(256) void k_sqnorm(const float* __restrict__ f,
                                                float* __restrict__ sq) {
    int i = blockIdx.x * 256 + threadIdx.x;   // b*N + n
    int b = i >> 13;
    int n = i & (N - 1);
    const float* fp = f + (size_t)b * C * N + n;
    float s = 0.f;
#pragma unroll
    for (int c = 0; c < C; ++c) {
        float v = fp[(size_t)c * N];
        s += v * v;
    }
    sq[i] = s;
}

// ---------------- kernel 2: KNN partial top-16 per segment ----------------
// grid = B * 128 * SEG blocks of 64 threads (1 wave).
// bid = b*1024 + qt*8 + seg ; each lane owns one query, iterates 1024 candidates.
__global__ __launch_bounds__(64) void k_knn(const float* __restrict__ f,
                                            const float* __restrict__ sq,
                                            float* __restrict__ partd,
                                            int* __restrict__ parti) {
    __shared__ __align__(16) float ldsP[TM * 68];  // [m][c], row stride 68 (272B, 16B aligned)
    __shared__ float ldsSq[TM];

    int bid = blockIdx.x;
    int seg = bid & 7;
    int qt  = (bid >> 3) & 127;
    int b   = bid >> 10;
    int lane = threadIdx.x;
    int q = qt * 64 + lane;
    const float* fb = f + (size_t)b * C * N;

    // query channels -> registers (coalesced per channel row)
    float qv[C];
#pragma unroll
    for (int c = 0; c < C; ++c) qv[c] = fb[(size_t)c * N + q];

    float bd[16];
    int   bi16[16];
#pragma unroll
    for (int j = 0; j < 16; ++j) { bd[j] = 3.4e38f; bi16[j] = -1; }
    float worst = 3.4e38f;
    int wslot = 0;

    int m0base = seg * (N / SEG);
    for (int t = 0; t < N / SEG; t += TM) {
        int m0 = m0base + t;
        __syncthreads();
        // stage TM candidates: thread `lane` owns candidate m0+lane's row
#pragma unroll
        for (int c = 0; c < C; ++c)
            ldsP[lane * 68 + c] = fb[(size_t)c * N + m0 + lane];
        ldsSq[lane] = sq[b * N + m0 + lane];
        __syncthreads();

        for (int mm = 0; mm < TM; ++mm) {
            const float4* p4 = reinterpret_cast<const float4*>(&ldsP[mm * 68]);
            float a0 = 0.f, a1 = 0.f, a2 = 0.f, a3 = 0.f;
#pragma unroll
            for (int c4 = 0; c4 < C / 4; ++c4) {
                float4 pv = p4[c4];        // broadcast b128 read
                a0 += qv[c4 * 4 + 0] * pv.x;
                a1 += qv[c4 * 4 + 1] * pv.y;
                a2 += qv[c4 * 4 + 2] * pv.z;
                a3 += qv[c4 * 4 + 3] * pv.w;
            }
            float key = ldsSq[mm] - 2.f * ((a0 + a1) + (a2 + a3));
            if (key < worst) {               // strict: ties keep earlier index
                int m = m0 + mm;
#pragma unroll
                for (int j = 0; j < 16; ++j)
                    if (j == wslot) { bd[j] = key; bi16[j] = m; }
                worst = bd[0]; wslot = 0;
#pragma unroll
                for (int j = 1; j < 16; ++j)
                    if (bd[j] > worst) { worst = bd[j]; wslot = j; }
            }
        }
    }

    // partials laid out [(seg*16+j)][b*N+q] for coalesced write + coalesced merge read
    int bq = b * N + q;
#pragma unroll
    for (int j = 0; j < 16; ++j) {
        partd[(seg * 16 + j) * (B * N) + bq] = bd[j];
        parti[(seg * 16 + j) * (B * N) + bq] = bi16[j];
    }
}

// ---------------- kernel 3: merge SEG partial lists -> nn_idx ----------------
__global__ __launch_bounds__(256) void k_merge(const float* __restrict__ partd,
                                               const int* __restrict__ parti,
                                               int* __restrict__ nn) {
    int i = blockIdx.x * 256 + threadIdx.x;   // b*N + q
    float bd[16];
    int   bi16[16];
#pragma unroll
    for (int j = 0; j < 16; ++j) { bd[j] = 3.4e38f; bi16[j] = -1; }
    float worst = 3.4e38f;
    int wslot = 0;
    for (int t = 0; t < SEG * 16; ++t) {
        float key = partd[t * (B * N) + i];
        int   idx = parti[t * (B * N) + i];
        if (key < worst) {
#pragma unroll
            for (int j = 0; j < 16; ++j)
                if (j == wslot) { bd[j] = key; bi16[j] = idx; }
            worst = bd[0]; wslot = 0;
#pragma unroll
            for (int j = 1; j < 16; ++j)
                if (bd[j] > worst) { worst = bd[j]; wslot = j; }
        }
    }
#pragma unroll
    for (int j = 0; j < 16; ++j) nn[i * 16 + j] = bi16[j];
}

// ---------------- kernel 4: A = W1*f, G = W2*f, stored [b][n][o] ----------------
__global__ __launch_bounds__(256) void k_ag(const float* __restrict__ f,
                                            const float* __restrict__ W,
                                            float* __restrict__ A,
                                            float* __restrict__ G) {
    __shared__ float lw[CO * 129];   // W[o][c] at lw[o*129+c]; (o*129+c)%32 == (o+c)%32 -> 2-way max
    __shared__ float lf[C * 64];     // f[c][nl]
    int bid = blockIdx.x;            // b*128 + nt
    int b = bid >> 7;
    int n0 = (bid & 127) * 64;
    int tid = threadIdx.x;

    for (int idx = tid; idx < CO * 128; idx += 256) {
        int o = idx >> 7, c = idx & 127;
        lw[o * 129 + c] = W[idx];
    }
    for (int idx = tid; idx < C * 64; idx += 256) {
        int c = idx >> 6, nl = idx & 63;
        lf[idx] = f[(size_t)b * C * N + (size_t)c * N + n0 + nl];
    }
    __syncthreads();

    int o = tid & 63, qq = tid >> 6;
    for (int ii = 0; ii < 16; ++ii) {
        int nl = qq * 16 + ii;
        float fa = 0.f, fg = 0.f;
#pragma unroll
        for (int c = 0; c < C; ++c) {
            float fv = lf[c * 64 + nl];          // broadcast
            fa += lw[o * 129 + c] * fv;
            fg += lw[o * 129 + 64 + c] * fv;
        }
        int n = n0 + nl;
        A[((size_t)b * N + n) * 64 + o] = fa;    // coalesced over o
        G[((size_t)b * N + n) * 64 + o] = fg;
    }
}

// ---------------- kernel 5: gather stats + per-(n,o) max/min ----------------
__global__ __launch_bounds__(256) void k_stats(const float* __restrict__ A,
                                               const float* __restrict__ G,
                                               const int* __restrict__ nn,
                                               float* __restrict__ ymax,
                                               float* __restrict__ ymin,
                                               float* __restrict__ stats) {
    __shared__ int lidx[64 * K];
    __shared__ float red[256];
    int bid = blockIdx.x;            // b*128 + nt
    int b = bid >> 7;
    int n0 = (bid & 127) * 64;
    int tid = threadIdx.x;

    for (int idx = tid; idx < 64 * K; idx += 256)
        lidx[idx] = nn[((size_t)b * N + n0) * K + idx];
    __syncthreads();

    int o = tid & 63, qq = tid >> 6;
    const float* Gb = G + (size_t)b * N * 64;
    float ssum = 0.f, ssq = 0.f;
    for (int ii = 0; ii < 16; ++ii) {
        int nl = qq * 16 + ii;
        int n = n0 + nl;
        float a = A[((size_t)b * N + n) * 64 + o];
        float g = Gb[(size_t)n * 64 + o];
        float d = a - g;
        float s1 = 0.f, s2 = 0.f;
        float gmx = -3.4e38f, gmn = 3.4e38f;
#pragma unroll
        for (int k = 0; k < K; ++k) {
            int j = lidx[nl * K + k];            // broadcast
            float gj = Gb[(size_t)j * 64 + o];   // 256B coalesced gather
            s1 += gj;
            s2 += gj * gj;
            gmx = fmaxf(gmx, gj);
            gmn = fminf(gmn, gj);
        }
        ymax[((size_t)b * N + n) * 64 + o] = d + gmx;
        ymin[((size_t)b * N + n) * 64 + o] = d + gmn;
        ssum += (float)K * d + s1;
        ssq  += (float)K * d * d + 2.f * d * s1 + s2;
    }

    red[tid] = ssum; __syncthreads();
    if (qq == 0) {
        float t = red[o] + red[64 + o] + red[128 + o] + red[192 + o];
        atomicAdd(&stats[o], t);
    }
    __syncthreads();
    red[tid] = ssq; __syncthreads();
    if (qq == 0) {
        float t = red[o] + red[64 + o] + red[128 + o] + red[192 + o];
        atomicAdd(&stats[64 + o], t);
    }
}

// ---------------- kernel 6: BN + leaky + max-over-k (via monotonicity) ----------------
__global__ __launch_bounds__(256) void k_final(const float* __restrict__ ymax,
                                               const float* __restrict__ ymin,
                                               const float* __restrict__ stats,
                                               const float* __restrict__ gamma,
                                               const float* __restrict__ beta,
                                               float* __restrict__ out) {
    __shared__ float lt[64 * 65];
    int bid = blockIdx.x;            // b*128 + nt
    int b = bid >> 7;
    int n0 = (bid & 127) * 64;
    int tid = threadIdx.x;
    int o = tid & 63, qq = tid >> 6;

    const float Mcnt = (float)(B * N * K);
    float s1 = stats[o], s2 = stats[64 + o];
    float mean = s1 / Mcnt;
    float var = s2 / Mcnt - mean * mean;
    float inv = rsqrtf(var + 1e-5f);
    float scale = gamma[o] * inv;
    float shift = beta[o] - mean * scale;
    const float* src = (scale >= 0.f) ? ymax : ymin;  // monotonic transform: max commutes

    for (int ii = 0; ii < 16; ++ii) {
        int nl = qq * 16 + ii;
        int n = n0 + nl;
        float v = src[((size_t)b * N + n) * 64 + o] * scale + shift;
        v = (v >= 0.f) ? v : 0.2f * v;
        lt[o * 65 + nl] = v;
    }
    __syncthreads();
    int nl2 = tid & 63;
    for (int ii = 0; ii < 16; ++ii) {
        int o2 = qq * 16 + ii;
        out[((size_t)b * CO + o2) * N + n0 + nl2] = lt[o2 * 65 + nl2];
    }
}

extern "C" void kernel_launch(void* const* d_in, const int* in_sizes, int n_in,
                              void* d_out, int out_size, void* d_ws, size_t ws_size,
                              hipStream_t stream) {
    const float* x     = (const float*)d_in[0];   // (B, C, N, 1) == (B, C, N)
    const float* W     = (const float*)d_in[1];   // (CO, 2C)
    const float* gamma = (const float*)d_in[2];
    const float* beta  = (const float*)d_in[3];
    float* out = (float*)d_out;

    char* ws = (char*)d_ws;
    // layout (bytes):
    //   sq      @ 0         : 64 KB
    //   stats   @ 65536     : 512 B
    //   nn      @ 131072    : 2 MB
    //   partd   @ 2228224   : 8 MB   (later reused: A @ same, G @ +4MB)
    //   parti   @ 10616832  : 8 MB   (later reused: ymax @ same, ymin @ +4MB)
    float* sq    = (float*)(ws + 0);
    float* stats = (float*)(ws + 65536);
    int*   nn    = (int*)  (ws + 131072);
    float* partd = (float*)(ws + 2228224);
    int*   parti = (int*)  (ws + 10616832);
    float* A     = (float*)(ws + 2228224);            // reuse partd after merge
    float* G     = (float*)(ws + 2228224 + 4194304);
    float* ymax  = (float*)(ws + 10616832);           // reuse parti after merge
    float* ymin  = (float*)(ws + 10616832 + 4194304);

    hipMemsetAsync(stats, 0, 512, stream);
    k_sqnorm<<<(B * N) / 256, 256, 0, stream>>>(x, sq);
    k_knn<<<B * 128 * SEG, 64, 0, stream>>>(x, sq, partd, parti);
    k_merge<<<(B * N) / 256, 256, 0, stream>>>(partd, parti, nn);
    k_ag<<<B * 128, 256, 0, stream>>>(x, W, A, G);
    k_stats<<<B * 128, 256, 0, stream>>>(A, G, nn, ymax, ymin, stats);
    k_final<<<B * 128, 256, 0, stream>>>(ymax, ymin, stats, gamma, beta, out);
}

// Round 11
// 575.269 us; speedup vs baseline: 1.5290x; 1.5290x over previous
//
#include <hip/hip_runtime.h>
#include <hip/hip_bf16.h>

#define B 2
#define C 64
#define N 8192
#define K 16
#define CO 64
#define KSEG 4
#define NSTEP (N / KSEG / 64)   // 32 candidate tiles of 64 per segment

using s8v    = __attribute__((ext_vector_type(8)))  short;
using f32x16 = __attribute__((ext_vector_type(16))) float;

__device__ __forceinline__ unsigned short f2bf(float f) {
    unsigned u = __builtin_bit_cast(unsigned, f);
    u += 0x7fffu + ((u >> 16) & 1u);
    return (unsigned short)(u >> 16);
}
__device__ __forceinline__ float bf2f(unsigned short h) {
    unsigned u = ((unsigned)h) << 16;
    return __builtin_bit_cast(float, u);
}
__device__ __forceinline__ void gl_lds16(const void* g, void* l) {
    __builtin_amdgcn_global_load_lds((const __attribute__((address_space(1))) unsigned int*)g,
                                     (__attribute__((address_space(3))) unsigned int*)l, 16, 0, 0);
}

// ---------------- kernel 1: per-point squared norms (fp32, exact) ----------------
__global__ __launch_bounds__(256) void k_sqnorm(const float* __restrict__ f,
                                                float* __restrict__ sq) {
    int i = blockIdx.x * 256 + threadIdx.x;   // b*N + n
    int b = i >> 13;
    int n = i & (N - 1);
    const float* fp = f + (size_t)b * C * N + n;
    float s = 0.f;
#pragma unroll
    for (int c = 0; c < C; ++c) {
        float v = fp[(size_t)c * N];
        s += v * v;
    }
    sq[i] = s;
}

// ---------------- kernel 1b: transpose + 3-way bf16 split: Xs[b][n][c] ----------------
__global__ __launch_bounds__(256) void k_prep(const float* __restrict__ x,
                                              unsigned short* __restrict__ Xh,
                                              unsigned short* __restrict__ Xm,
                                              unsigned short* __restrict__ Xl) {
    __shared__ float lt[64][65];
    int bid = blockIdx.x;            // b*128 + nt
    int b = bid >> 7;
    int n0 = (bid & 127) * 64;
    int tid = threadIdx.x;
    int quarter = tid >> 6, j = tid & 63;
#pragma unroll
    for (int cc = 0; cc < 16; ++cc) {
        int c = quarter * 16 + cc;
        lt[c][j] = x[((size_t)b * C + c) * N + n0 + j];   // coalesced over j
    }
    __syncthreads();
#pragma unroll
    for (int cc = 0; cc < 16; ++cc) {
        int nl = quarter * 16 + cc;
        float v = lt[j][nl];                              // pad-65: conflict-free
        unsigned short h = f2bf(v);
        float r1 = v - bf2f(h);
        unsigned short m = f2bf(r1);
        unsigned short l = f2bf(r1 - bf2f(m));
        size_t row = ((size_t)b * N + n0 + nl) * 64 + j;  // coalesced 128B rows
        Xh[row] = h; Xm[row] = m; Xl[row] = l;
    }
}

// ---------------- kernel 2: MFMA KNN, 6-term bf16-split distances ----------------
// grid = 512 blocks x 256 thr. bid: seg=bid&3, qb=(bid>>2)&63, b=bid>>8.
// Wave w owns queries qb*128 + w*32 .. +31 (B-operand, frags in regs).
// Candidates staged 64/tile into dbuf LDS (swizzled), A-operand.
__global__ __launch_bounds__(256, 2) void k_knn(
        const unsigned short* __restrict__ Xh,
        const unsigned short* __restrict__ Xm,
        const unsigned short* __restrict__ Xl,
        const float* __restrict__ sq,
        float* __restrict__ partd, int* __restrict__ parti) {
    __shared__ __align__(16) unsigned short lds[2][3][64 * 64];

    int bid = blockIdx.x;
    int seg = bid & 3;
    int qb  = (bid >> 2) & 63;
    int b   = bid >> 8;
    int tid = threadIdx.x;
    int w = tid >> 6, lane = tid & 63;
    int l31 = lane & 31, lhi = lane >> 5;     // 0/1
    int q = qb * 128 + w * 32 + l31;

    const unsigned short* Xs[3] = {Xh, Xm, Xl};

    // B-frags (queries), loaded once: qf[split][kt]
    s8v qf[3][4];
    {
        size_t qrow = ((size_t)b * N + q) * 64;
#pragma unroll
        for (int s = 0; s < 3; ++s)
#pragma unroll
            for (int kt = 0; kt < 4; ++kt)
                qf[s][kt] = *(const s8v*)&Xs[s][qrow + kt * 16 + lhi * 8];
    }

    // top-16 max-list of score = inner - sq/2
    float bd[16];
    int   bi16[16];
#pragma unroll
    for (int j = 0; j < 16; ++j) { bd[j] = -3.4e38f; bi16[j] = -1; }
    float worst = -3.4e38f;
    int wslot = 0;

    int segbase = seg * (N / KSEG);
    int srcRowOff = lane >> 3;                 // 0..7
    int srcChunk  = (lane & 7) ^ (lane >> 3);  // pre-swizzled source chunk

    // prologue: stage tile 0 into buf 0 (6 issues per wave)
    {
        int cand0 = segbase;
#pragma unroll
        for (int jj = 0; jj < 6; ++jj) {
            int is = w * 6 + jj;
            int split = is >> 3, r0 = (is & 7) * 8;
            const unsigned short* gsrc = Xs[split] +
                ((size_t)(b * N + cand0 + r0 + srcRowOff)) * 64 + srcChunk * 8;
            gl_lds16(gsrc, &lds[0][split][r0 * 64]);
        }
    }

    for (int t = 0; t < NSTEP; ++t) {
        int cand0 = segbase + t * 64;
        int cb = t & 1;

        // (1) sq loads + acc init (compiler waits these before stage issues)
        f32x16 acc[2];
#pragma unroll
        for (int ct = 0; ct < 2; ++ct) {
#pragma unroll
            for (int g = 0; g < 4; ++g) {
                float4 sv = *(const float4*)&sq[b * N + cand0 + ct * 32 + g * 8 + 4 * lhi];
                acc[ct][g * 4 + 0] = -0.5f * sv.x;
                acc[ct][g * 4 + 1] = -0.5f * sv.y;
                acc[ct][g * 4 + 2] = -0.5f * sv.z;
                acc[ct][g * 4 + 3] = -0.5f * sv.w;
            }
        }
        asm volatile("" ::: "memory");

        // (2) stage next tile into the other buffer
        if (t + 1 < NSTEP) {
            int cn = cand0 + 64;
#pragma unroll
            for (int jj = 0; jj < 6; ++jj) {
                int is = w * 6 + jj;
                int split = is >> 3, r0 = (is & 7) * 8;
                const unsigned short* gsrc = Xs[split] +
                    ((size_t)(b * N + cn + r0 + srcRowOff)) * 64 + srcChunk * 8;
                gl_lds16(gsrc, &lds[cb ^ 1][split][r0 * 64]);
            }
            // (3) wait: drain this tile's 6 stages, keep next tile's 6 in flight
            asm volatile("s_waitcnt vmcnt(6)" ::: "memory");
        } else {
            asm volatile("s_waitcnt vmcnt(0)" ::: "memory");
        }
        __syncthreads();

        // (4) compute: 2 cand-subtiles x 4 kt x 6 terms = 48 MFMA
#pragma unroll
        for (int ct = 0; ct < 2; ++ct) {
            int arow = ct * 32 + l31;
            s8v af[3][4];
#pragma unroll
            for (int s = 0; s < 3; ++s)
#pragma unroll
                for (int kt = 0; kt < 4; ++kt)
                    af[s][kt] = *(const s8v*)&lds[cb][s][arow * 64 + (((kt * 2 + lhi) ^ (arow & 7)) * 8)];
            f32x16 a = acc[ct];
#pragma unroll
            for (int kt = 0; kt < 4; ++kt) {
                a = __builtin_amdgcn_mfma_f32_32x32x16_bf16(af[1][kt], qf[1][kt], a, 0, 0, 0); // m*m
                a = __builtin_amdgcn_mfma_f32_32x32x16_bf16(af[0][kt], qf[2][kt], a, 0, 0, 0); // h*l
                a = __builtin_amdgcn_mfma_f32_32x32x16_bf16(af[2][kt], qf[0][kt], a, 0, 0, 0); // l*h
                a = __builtin_amdgcn_mfma_f32_32x32x16_bf16(af[0][kt], qf[1][kt], a, 0, 0, 0); // h*m
                a = __builtin_amdgcn_mfma_f32_32x32x16_bf16(af[1][kt], qf[0][kt], a, 0, 0, 0); // m*h
                a = __builtin_amdgcn_mfma_f32_32x32x16_bf16(af[0][kt], qf[0][kt], a, 0, 0, 0); // h*h
            }
            // (5) top-16 select; lane owns rows (r&3)+8*(r>>2)+4*lhi of this 32-subtile
#pragma unroll
            for (int r = 0; r < 16; ++r) {
                float sc = a[r];
                if (sc > worst) {
                    int idx = cand0 + ct * 32 + (r & 3) + 8 * (r >> 2) + 4 * lhi;
#pragma unroll
                    for (int j = 0; j < 16; ++j)
                        if (j == wslot) { bd[j] = sc; bi16[j] = idx; }
                    worst = bd[0]; wslot = 0;
#pragma unroll
                    for (int j = 1; j < 16; ++j)
                        if (bd[j] < worst) { worst = bd[j]; wslot = j; }
                }
            }
        }
        __syncthreads();
    }

    // 8 lists per query: listid = seg*2 + rowhalf. Store key = -score (min-merge).
    int listid = seg * 2 + lhi;
    int bq = b * N + q;
#pragma unroll
    for (int j = 0; j < 16; ++j) {
        partd[(listid * 16 + j) * (B * N) + bq] = -bd[j];
        parti[(listid * 16 + j) * (B * N) + bq] = bi16[j];
    }
}

// ---------------- kernel 3: merge 8 partial lists -> nn_idx ----------------
__global__ __launch_bounds__(256) void k_merge(const float* __restrict__ partd,
                                               const int* __restrict__ parti,
                                               int* __restrict__ nn) {
    int i = blockIdx.x * 256 + threadIdx.x;   // b*N + q
    float bd[16];
    int   bi16[16];
#pragma unroll
    for (int j = 0; j < 16; ++j) { bd[j] = 3.4e38f; bi16[j] = -1; }
    float worst = 3.4e38f;
    int wslot = 0;
    for (int t = 0; t < 8 * 16; ++t) {
        float key = partd[t * (B * N) + i];
        int   idx = parti[t * (B * N) + i];
        if (key < worst) {
#pragma unroll
            for (int j = 0; j < 16; ++j)
                if (j == wslot) { bd[j] = key; bi16[j] = idx; }
            worst = bd[0]; wslot = 0;
#pragma unroll
            for (int j = 1; j < 16; ++j)
                if (bd[j] > worst) { worst = bd[j]; wslot = j; }
        }
    }
#pragma unroll
    for (int j = 0; j < 16; ++j) nn[i * 16 + j] = bi16[j];
}

// ---------------- kernel 4: A = W1*f, G = W2*f, stored [b][n][o] ----------------
__global__ __launch_bounds__(256) void k_ag(const float* __restrict__ f,
                                            const float* __restrict__ W,
                                            float* __restrict__ A,
                                            float* __restrict__ G) {
    __shared__ float lw[CO * 129];
    __shared__ float lf[C * 64];
    int bid = blockIdx.x;            // b*128 + nt
    int b = bid >> 7;
    int n0 = (bid & 127) * 64;
    int tid = threadIdx.x;

    for (int idx = tid; idx < CO * 128; idx += 256) {
        int o = idx >> 7, c = idx & 127;
        lw[o * 129 + c] = W[idx];
    }
    for (int idx = tid; idx < C * 64; idx += 256) {
        int c = idx >> 6, nl = idx & 63;
        lf[idx] = f[(size_t)b * C * N + (size_t)c * N + n0 + nl];
    }
    __syncthreads();

    int o = tid & 63, qq = tid >> 6;
    for (int ii = 0; ii < 16; ++ii) {
        int nl = qq * 16 + ii;
        float fa = 0.f, fg = 0.f;
#pragma unroll
        for (int c = 0; c < C; ++c) {
            float fv = lf[c * 64 + nl];
            fa += lw[o * 129 + c] * fv;
            fg += lw[o * 129 + 64 + c] * fv;
        }
        int n = n0 + nl;
        A[((size_t)b * N + n) * 64 + o] = fa;
        G[((size_t)b * N + n) * 64 + o] = fg;
    }
}

// ---------------- kernel 5: gather stats + per-(n,o) max/min ----------------
__global__ __launch_bounds__(256) void k_stats(const float* __restrict__ A,
                                               const float* __restrict__ G,
                                               const int* __restrict__ nn,
                                               float* __restrict__ ymax,
                                               float* __restrict__ ymin,
                                               float* __restrict__ stats) {
    __shared__ int lidx[64 * K];
    __shared__ float red[256];
    int bid = blockIdx.x;            // b*128 + nt
    int b = bid >> 7;
    int n0 = (bid & 127) * 64;
    int tid = threadIdx.x;

    for (int idx = tid; idx < 64 * K; idx += 256)
        lidx[idx] = nn[((size_t)b * N + n0) * K + idx];
    __syncthreads();

    int o = tid & 63, qq = tid >> 6;
    const float* Gb = G + (size_t)b * N * 64;
    float ssum = 0.f, ssq = 0.f;
    for (int ii = 0; ii < 16; ++ii) {
        int nl = qq * 16 + ii;
        int n = n0 + nl;
        float a = A[((size_t)b * N + n) * 64 + o];
        float g = Gb[(size_t)n * 64 + o];
        float d = a - g;
        float s1 = 0.f, s2 = 0.f;
        float gmx = -3.4e38f, gmn = 3.4e38f;
#pragma unroll
        for (int k = 0; k < K; ++k) {
            int j = lidx[nl * K + k];
            float gj = Gb[(size_t)j * 64 + o];
            s1 += gj;
            s2 += gj * gj;
            gmx = fmaxf(gmx, gj);
            gmn = fminf(gmn, gj);
        }
        ymax[((size_t)b * N + n) * 64 + o] = d + gmx;
        ymin[((size_t)b * N + n) * 64 + o] = d + gmn;
        ssum += (float)K * d + s1;
        ssq  += (float)K * d * d + 2.f * d * s1 + s2;
    }

    red[tid] = ssum; __syncthreads();
    if (qq == 0) {
        float t = red[o] + red[64 + o] + red[128 + o] + red[192 + o];
        atomicAdd(&stats[o], t);
    }
    __syncthreads();
    red[tid] = ssq; __syncthreads();
    if (qq == 0) {
        float t = red[o] + red[64 + o] + red[128 + o] + red[192 + o];
        atomicAdd(&stats[64 + o], t);
    }
}

// ---------------- kernel 6: BN + leaky + max-over-k (monotonicity) ----------------
__global__ __launch_bounds__(256) void k_final(const float* __restrict__ ymax,
                                               const float* __restrict__ ymin,
                                               const float* __restrict__ stats,
                                               const float* __restrict__ gamma,
                                               const float* __restrict__ beta,
                                               float* __restrict__ out) {
    __shared__ float lt[64 * 65];
    int bid = blockIdx.x;            // b*128 + nt
    int b = bid >> 7;
    int n0 = (bid & 127) * 64;
    int tid = threadIdx.x;
    int o = tid & 63, qq = tid >> 6;

    const float Mcnt = (float)(B * N * K);
    float s1 = stats[o], s2 = stats[64 + o];
    float mean = s1 / Mcnt;
    float var = s2 / Mcnt - mean * mean;
    float inv = rsqrtf(var + 1e-5f);
    float scale = gamma[o] * inv;
    float shift = beta[o] - mean * scale;
    const float* src = (scale >= 0.f) ? ymax : ymin;

    for (int ii = 0; ii < 16; ++ii) {
        int nl = qq * 16 + ii;
        int n = n0 + nl;
        float v = src[((size_t)b * N + n) * 64 + o] * scale + shift;
        v = (v >= 0.f) ? v : 0.2f * v;
        lt[o * 65 + nl] = v;
    }
    __syncthreads();
    int nl2 = tid & 63;
    for (int ii = 0; ii < 16; ++ii) {
        int o2 = qq * 16 + ii;
        out[((size_t)b * CO + o2) * N + n0 + nl2] = lt[o2 * 65 + nl2];
    }
}

extern "C" void kernel_launch(void* const* d_in, const int* in_sizes, int n_in,
                              void* d_out, int out_size, void* d_ws, size_t ws_size,
                              hipStream_t stream) {
    const float* x     = (const float*)d_in[0];   // (B, C, N, 1)
    const float* W     = (const float*)d_in[1];   // (CO, 2C)
    const float* gamma = (const float*)d_in[2];
    const float* beta  = (const float*)d_in[3];
    float* out = (float*)d_out;

    char* ws = (char*)d_ws;
    // layout (bytes):
    //   sq    @ 0          : 64 KB
    //   stats @ 65536      : 512 B
    //   nn    @ 131072     : 2 MB
    //   partd @ 2228224    : 8 MB   (reused after merge: A, G)
    //   parti @ 10616832   : 8 MB   (reused after merge: ymax, ymin)
    //   Xh    @ 19005440   : 2 MB
    //   Xm    @ 21102592   : 2 MB
    //   Xl    @ 23199744   : 2 MB   (total 25.3 MB)
    float*          sq    = (float*)(ws + 0);
    float*          stats = (float*)(ws + 65536);
    int*            nn    = (int*)  (ws + 131072);
    float*          partd = (float*)(ws + 2228224);
    int*            parti = (int*)  (ws + 10616832);
    float*          A     = (float*)(ws + 2228224);
    float*          G     = (float*)(ws + 2228224 + 4194304);
    float*          ymax  = (float*)(ws + 10616832);
    float*          ymin  = (float*)(ws + 10616832 + 4194304);
    unsigned short* Xh    = (unsigned short*)(ws + 19005440);
    unsigned short* Xm    = (unsigned short*)(ws + 21102592);
    unsigned short* Xl    = (unsigned short*)(ws + 23199744);

    hipMemsetAsync(stats, 0, 512, stream);
    k_sqnorm<<<(B * N) / 256, 256, 0, stream>>>(x, sq);
    k_prep  <<<B * 128, 256, 0, stream>>>(x, Xh, Xm, Xl);
    k_knn   <<<B * 64 * KSEG, 256, 0, stream>>>(Xh, Xm, Xl, sq, partd, parti);
    k_merge <<<(B * N) / 256, 256, 0, stream>>>(partd, parti, nn);
    k_ag    <<<B * 128, 256, 0, stream>>>(x, W, A, G);
    k_stats <<<B * 128, 256, 0, stream>>>(A, G, nn, ymax, ymin, stats);
    k_final <<<B * 128, 256, 0, stream>>>(ymax, ymin, stats, gamma, beta, out);
}

// Round 12
// 489.046 us; speedup vs baseline: 1.7986x; 1.1763x over previous
//
#include <hip/hip_runtime.h>
#include <hip/hip_bf16.h>

#define B 2
#define C 64
#define N 8192
#define K 16
#define CO 64
#define KSEG 4
#define NSTEP (N / KSEG / 64)   // 32 candidate tiles of 64 per segment

using s8v    = __attribute__((ext_vector_type(8)))  short;
using f32x16 = __attribute__((ext_vector_type(16))) float;

__device__ __forceinline__ unsigned short f2bf(float f) {
    unsigned u = __builtin_bit_cast(unsigned, f);
    u += 0x7fffu + ((u >> 16) & 1u);
    return (unsigned short)(u >> 16);
}
__device__ __forceinline__ float bf2f(unsigned short h) {
    unsigned u = ((unsigned)h) << 16;
    return __builtin_bit_cast(float, u);
}
__device__ __forceinline__ void gl_lds16(const void* g, void* l) {
    __builtin_amdgcn_global_load_lds((const __attribute__((address_space(1))) unsigned int*)g,
                                     (__attribute__((address_space(3))) unsigned int*)l, 16, 0, 0);
}

// ---- kernel 1: transpose + 3-way bf16 split + fused (-sq/2) ----
// Xs[b][n][c] layout; nsq[b*N+n] = -0.5*||x_n||^2
__global__ __launch_bounds__(256) void k_prep(const float* __restrict__ x,
                                              unsigned short* __restrict__ Xh,
                                              unsigned short* __restrict__ Xm,
                                              unsigned short* __restrict__ Xl,
                                              float* __restrict__ nsq) {
    __shared__ float lt[64][65];
    __shared__ float red[4 * 64];
    int bid = blockIdx.x;            // b*128 + nt
    int b = bid >> 7;
    int n0 = (bid & 127) * 64;
    int tid = threadIdx.x;
    int quarter = tid >> 6, j = tid & 63;
    float part = 0.f;
#pragma unroll
    for (int cc = 0; cc < 16; ++cc) {
        int c = quarter * 16 + cc;
        float v = x[((size_t)b * C + c) * N + n0 + j];    // coalesced over j
        lt[c][j] = v;
        part += v * v;                                    // partial ||x_{n0+j}||^2
    }
    red[quarter * 64 + j] = part;
    __syncthreads();
    if (quarter == 0)
        nsq[b * N + n0 + j] = -0.5f * (red[j] + red[64 + j] + red[128 + j] + red[192 + j]);
#pragma unroll
    for (int cc = 0; cc < 16; ++cc) {
        int nl = quarter * 16 + cc;
        float v = lt[j][nl];                              // pad-65: conflict-free
        unsigned short h = f2bf(v);
        float r1 = v - bf2f(h);
        unsigned short m = f2bf(r1);
        unsigned short l = f2bf(r1 - bf2f(m));
        size_t row = ((size_t)b * N + n0 + nl) * 64 + j;  // coalesced 128B rows
        Xh[row] = h; Xm[row] = m; Xl[row] = l;
    }
}

// ---- kernel 2: MFMA KNN, 6-term bf16-split distances ----
// grid = 512 blocks x 256 thr. bid: seg=bid&3, qb=(bid>>2)&63, b=bid>>8.
// Wave w owns queries qb*128 + w*32 .. +31 (B-operand frags in regs).
// Candidates staged 64/tile into dbuf LDS (swizzled), A-operand.
// Top-16: slot-packed scores (low-4 mantissa bits = slot), indices in LDS.
__global__ __launch_bounds__(256, 2) void k_knn(
        const unsigned short* __restrict__ Xh,
        const unsigned short* __restrict__ Xm,
        const unsigned short* __restrict__ Xl,
        const float* __restrict__ nsq,
        float* __restrict__ partd, int* __restrict__ parti) {
    __shared__ __align__(16) unsigned short lds[2][3][64 * 64];
    __shared__ int lidx[256 * 16];   // per-thread 16-entry index list

    int bid = blockIdx.x;
    int seg = bid & 3;
    int qb  = (bid >> 2) & 63;
    int b   = bid >> 8;
    int tid = threadIdx.x;
    int w = tid >> 6, lane = tid & 63;
    int l31 = lane & 31, lhi = lane >> 5;     // 0/1
    int q = qb * 128 + w * 32 + l31;

    const unsigned short* Xs[3] = {Xh, Xm, Xl};

    // B-frags (queries), loaded once: qf[split][kt]
    s8v qf[3][4];
    {
        size_t qrow = ((size_t)b * N + q) * 64;
#pragma unroll
        for (int s = 0; s < 3; ++s)
#pragma unroll
            for (int kt = 0; kt < 4; ++kt)
                qf[s][kt] = *(const s8v*)&Xs[s][qrow + kt * 16 + lhi * 8];
    }

    // top-16 max-list of score = inner - sq/2. Values slot-packed in low 4 bits.
    float bd[16];
#pragma unroll
    for (int j = 0; j < 16; ++j)
        bd[j] = __builtin_bit_cast(float, 0xFF7FFFF0u | (unsigned)j);  // ~ -FLT_MAX, finite
    float wmin = __builtin_bit_cast(float, 0xFF7FFFFFu);               // slot 15 is min
    int wslot = 15;

    int segbase = seg * (N / KSEG);
    int srcRowOff = lane >> 3;                 // 0..7
    int srcChunk  = (lane & 7) ^ (lane >> 3);  // pre-swizzled source chunk

    // prologue: stage tile 0 into buf 0 (6 issues per wave)
    {
        int cand0 = segbase;
#pragma unroll
        for (int jj = 0; jj < 6; ++jj) {
            int is = w * 6 + jj;
            int split = is >> 3, r0 = (is & 7) * 8;
            const unsigned short* gsrc = Xs[split] +
                ((size_t)(b * N + cand0 + r0 + srcRowOff)) * 64 + srcChunk * 8;
            gl_lds16(gsrc, &lds[0][split][r0 * 64]);
        }
    }

    for (int t = 0; t < NSTEP; ++t) {
        int cand0 = segbase + t * 64;
        int cb = t & 1;

        // (1) acc init from pre-negated-halved norms
        f32x16 acc[2];
#pragma unroll
        for (int ct = 0; ct < 2; ++ct) {
#pragma unroll
            for (int g = 0; g < 4; ++g) {
                float4 sv = *(const float4*)&nsq[b * N + cand0 + ct * 32 + g * 8 + 4 * lhi];
                acc[ct][g * 4 + 0] = sv.x;
                acc[ct][g * 4 + 1] = sv.y;
                acc[ct][g * 4 + 2] = sv.z;
                acc[ct][g * 4 + 3] = sv.w;
            }
        }
        asm volatile("" ::: "memory");

        // (2) stage next tile into the other buffer
        if (t + 1 < NSTEP) {
            int cn = cand0 + 64;
#pragma unroll
            for (int jj = 0; jj < 6; ++jj) {
                int is = w * 6 + jj;
                int split = is >> 3, r0 = (is & 7) * 8;
                const unsigned short* gsrc = Xs[split] +
                    ((size_t)(b * N + cn + r0 + srcRowOff)) * 64 + srcChunk * 8;
                gl_lds16(gsrc, &lds[cb ^ 1][split][r0 * 64]);
            }
            // (3) drain this tile's 6 stages, keep next tile's 6 in flight
            asm volatile("s_waitcnt vmcnt(6)" ::: "memory");
        } else {
            asm volatile("s_waitcnt vmcnt(0)" ::: "memory");
        }
        __syncthreads();

        // (4) compute: 2 cand-subtiles x 4 kt x 6 terms = 48 MFMA
#pragma unroll
        for (int ct = 0; ct < 2; ++ct) {
            int arow = ct * 32 + l31;
            s8v af[3][4];
#pragma unroll
            for (int s = 0; s < 3; ++s)
#pragma unroll
                for (int kt = 0; kt < 4; ++kt)
                    af[s][kt] = *(const s8v*)&lds[cb][s][arow * 64 + (((kt * 2 + lhi) ^ (arow & 7)) * 8)];
            f32x16 a = acc[ct];
#pragma unroll
            for (int kt = 0; kt < 4; ++kt) {
                a = __builtin_amdgcn_mfma_f32_32x32x16_bf16(af[1][kt], qf[1][kt], a, 0, 0, 0); // m*m
                a = __builtin_amdgcn_mfma_f32_32x32x16_bf16(af[0][kt], qf[2][kt], a, 0, 0, 0); // h*l
                a = __builtin_amdgcn_mfma_f32_32x32x16_bf16(af[2][kt], qf[0][kt], a, 0, 0, 0); // l*h
                a = __builtin_amdgcn_mfma_f32_32x32x16_bf16(af[0][kt], qf[1][kt], a, 0, 0, 0); // h*m
                a = __builtin_amdgcn_mfma_f32_32x32x16_bf16(af[1][kt], qf[0][kt], a, 0, 0, 0); // m*h
                a = __builtin_amdgcn_mfma_f32_32x32x16_bf16(af[0][kt], qf[0][kt], a, 0, 0, 0); // h*h
            }
            // (5) top-16 select; lane owns rows (r&3)+8*(r>>2)+4*lhi of this 32-subtile
#pragma unroll
            for (int r = 0; r < 16; ++r) {
                float sc = a[r];
                if (sc > wmin) {
                    int idx = cand0 + ct * 32 + (r & 3) + 8 * (r >> 2) + 4 * lhi;
                    unsigned pv = __builtin_bit_cast(unsigned, sc) & ~15u;
#pragma unroll
                    for (int j = 0; j < 16; ++j)
                        if (wslot == j) bd[j] = __builtin_bit_cast(float, pv | (unsigned)j);
                    lidx[(tid << 4) | wslot] = idx;          // dynamic LDS write
                    // rescan: pure min tree, argmin comes free from packed slot bits
                    float m0 = fminf(fminf(bd[0],  bd[1]),  fminf(bd[2],  bd[3]));
                    float m1 = fminf(fminf(bd[4],  bd[5]),  fminf(bd[6],  bd[7]));
                    float m2 = fminf(fminf(bd[8],  bd[9]),  fminf(bd[10], bd[11]));
                    float m3 = fminf(fminf(bd[12], bd[13]), fminf(bd[14], bd[15]));
                    wmin = fminf(fminf(m0, m1), fminf(m2, m3));
                    wslot = (int)(__builtin_bit_cast(unsigned, wmin) & 15u);
                }
            }
        }
        __syncthreads();
    }

    // 8 lists per query: listid = seg*2 + rowhalf. Store key = -score (min-merge).
    int listid = seg * 2 + lhi;
    int bq = b * N + q;
    int base = tid << 4;
#pragma unroll
    for (int j = 0; j < 16; ++j) {
        partd[(listid * 16 + j) * (B * N) + bq] = -bd[j];
        parti[(listid * 16 + j) * (B * N) + bq] = lidx[base + j];
    }
}

// ---- kernel 3: merge 8 partial lists -> nn_idx ----
__global__ __launch_bounds__(256) void k_merge(const float* __restrict__ partd,
                                               const int* __restrict__ parti,
                                               int* __restrict__ nn) {
    int i = blockIdx.x * 256 + threadIdx.x;   // b*N + q
    float bd[16];
    int   bi16[16];
#pragma unroll
    for (int j = 0; j < 16; ++j) { bd[j] = 3.4e38f; bi16[j] = -1; }
    float worst = 3.4e38f;
    int wslot = 0;
    for (int t = 0; t < 8 * 16; ++t) {
        float key = partd[t * (B * N) + i];
        int   idx = parti[t * (B * N) + i];
        if (key < worst) {
#pragma unroll
            for (int j = 0; j < 16; ++j)
                if (j == wslot) { bd[j] = key; bi16[j] = idx; }
            worst = bd[0]; wslot = 0;
#pragma unroll
            for (int j = 1; j < 16; ++j)
                if (bd[j] > worst) { worst = bd[j]; wslot = j; }
        }
    }
#pragma unroll
    for (int j = 0; j < 16; ++j) nn[i * 16 + j] = bi16[j];
}

// ---- kernel 4: A = W1*f, G = W2*f, stored [b][n][o] ----
__global__ __launch_bounds__(256) void k_ag(const float* __restrict__ f,
                                            const float* __restrict__ W,
                                            float* __restrict__ A,
                                            float* __restrict__ G) {
    __shared__ float lw[CO * 129];
    __shared__ float lf[C * 64];
    int bid = blockIdx.x;            // b*128 + nt
    int b = bid >> 7;
    int n0 = (bid & 127) * 64;
    int tid = threadIdx.x;

    for (int idx = tid; idx < CO * 128; idx += 256) {
        int o = idx >> 7, c = idx & 127;
        lw[o * 129 + c] = W[idx];
    }
    for (int idx = tid; idx < C * 64; idx += 256) {
        int c = idx >> 6, nl = idx & 63;
        lf[idx] = f[(size_t)b * C * N + (size_t)c * N + n0 + nl];
    }
    __syncthreads();

    int o = tid & 63, qq = tid >> 6;
    for (int ii = 0; ii < 16; ++ii) {
        int nl = qq * 16 + ii;
        float fa = 0.f, fg = 0.f;
#pragma unroll
        for (int c = 0; c < C; ++c) {
            float fv = lf[c * 64 + nl];
            fa += lw[o * 129 + c] * fv;
            fg += lw[o * 129 + 64 + c] * fv;
        }
        int n = n0 + nl;
        A[((size_t)b * N + n) * 64 + o] = fa;
        G[((size_t)b * N + n) * 64 + o] = fg;
    }
}

// ---- kernel 5: gather stats + per-(n,o) max/min ----
__global__ __launch_bounds__(256) void k_stats(const float* __restrict__ A,
                                               const float* __restrict__ G,
                                               const int* __restrict__ nn,
                                               float* __restrict__ ymax,
                                               float* __restrict__ ymin,
                                               float* __restrict__ stats) {
    __shared__ int lidx[64 * K];
    __shared__ float red[256];
    int bid = blockIdx.x;            // b*128 + nt
    int b = bid >> 7;
    int n0 = (bid & 127) * 64;
    int tid = threadIdx.x;

    for (int idx = tid; idx < 64 * K; idx += 256)
        lidx[idx] = nn[((size_t)b * N + n0) * K + idx];
    __syncthreads();

    int o = tid & 63, qq = tid >> 6;
    const float* Gb = G + (size_t)b * N * 64;
    float ssum = 0.f, ssq = 0.f;
    for (int ii = 0; ii < 16; ++ii) {
        int nl = qq * 16 + ii;
        int n = n0 + nl;
        float a = A[((size_t)b * N + n) * 64 + o];
        float g = Gb[(size_t)n * 64 + o];
        float d = a - g;
        float s1 = 0.f, s2 = 0.f;
        float gmx = -3.4e38f, gmn = 3.4e38f;
#pragma unroll
        for (int k = 0; k < K; ++k) {
            int j = lidx[nl * K + k];
            float gj = Gb[(size_t)j * 64 + o];
            s1 += gj;
            s2 += gj * gj;
            gmx = fmaxf(gmx, gj);
            gmn = fminf(gmn, gj);
        }
        ymax[((size_t)b * N + n) * 64 + o] = d + gmx;
        ymin[((size_t)b * N + n) * 64 + o] = d + gmn;
        ssum += (float)K * d + s1;
        ssq  += (float)K * d * d + 2.f * d * s1 + s2;
    }

    red[tid] = ssum; __syncthreads();
    if (qq == 0) {
        float t = red[o] + red[64 + o] + red[128 + o] + red[192 + o];
        atomicAdd(&stats[o], t);
    }
    __syncthreads();
    red[tid] = ssq; __syncthreads();
    if (qq == 0) {
        float t = red[o] + red[64 + o] + red[128 + o] + red[192 + o];
        atomicAdd(&stats[64 + o], t);
    }
}

// ---- kernel 6: BN + leaky + max-over-k (monotonicity) ----
__global__ __launch_bounds__(256) void k_final(const float* __restrict__ ymax,
                                               const float* __restrict__ ymin,
                                               const float* __restrict__ stats,
                                               const float* __restrict__ gamma,
                                               const float* __restrict__ beta,
                                               float* __restrict__ out) {
    __shared__ float lt[64 * 65];
    int bid = blockIdx.x;            // b*128 + nt
    int b = bid >> 7;
    int n0 = (bid & 127) * 64;
    int tid = threadIdx.x;
    int o = tid & 63, qq = tid >> 6;

    const float Mcnt = (float)(B * N * K);
    float s1 = stats[o], s2 = stats[64 + o];
    float mean = s1 / Mcnt;
    float var = s2 / Mcnt - mean * mean;
    float inv = rsqrtf(var + 1e-5f);
    float scale = gamma[o] * inv;
    float shift = beta[o] - mean * scale;
    const float* src = (scale >= 0.f) ? ymax : ymin;

    for (int ii = 0; ii < 16; ++ii) {
        int nl = qq * 16 + ii;
        int n = n0 + nl;
        float v = src[((size_t)b * N + n) * 64 + o] * scale + shift;
        v = (v >= 0.f) ? v : 0.2f * v;
        lt[o * 65 + nl] = v;
    }
    __syncthreads();
    int nl2 = tid & 63;
    for (int ii = 0; ii < 16; ++ii) {
        int o2 = qq * 16 + ii;
        out[((size_t)b * CO + o2) * N + n0 + nl2] = lt[o2 * 65 + nl2];
    }
}

extern "C" void kernel_launch(void* const* d_in, const int* in_sizes, int n_in,
                              void* d_out, int out_size, void* d_ws, size_t ws_size,
                              hipStream_t stream) {
    const float* x     = (const float*)d_in[0];   // (B, C, N, 1)
    const float* W     = (const float*)d_in[1];   // (CO, 2C)
    const float* gamma = (const float*)d_in[2];
    const float* beta  = (const float*)d_in[3];
    float* out = (float*)d_out;

    char* ws = (char*)d_ws;
    // layout (bytes):
    //   nsq   @ 0          : 64 KB   (-||x||^2 / 2)
    //   stats @ 65536      : 512 B
    //   nn    @ 131072     : 2 MB
    //   partd @ 2228224    : 8 MB   (reused after merge: A, G)
    //   parti @ 10616832   : 8 MB   (reused after merge: ymax, ymin)
    //   Xh    @ 19005440   : 2 MB
    //   Xm    @ 21102592   : 2 MB
    //   Xl    @ 23199744   : 2 MB   (total 25.3 MB)
    float*          nsq   = (float*)(ws + 0);
    float*          stats = (float*)(ws + 65536);
    int*            nn    = (int*)  (ws + 131072);
    float*          partd = (float*)(ws + 2228224);
    int*            parti = (int*)  (ws + 10616832);
    float*          A     = (float*)(ws + 2228224);
    float*          G     = (float*)(ws + 2228224 + 4194304);
    float*          ymax  = (float*)(ws + 10616832);
    float*          ymin  = (float*)(ws + 10616832 + 4194304);
    unsigned short* Xh    = (unsigned short*)(ws + 19005440);
    unsigned short* Xm    = (unsigned short*)(ws + 21102592);
    unsigned short* Xl    = (unsigned short*)(ws + 23199744);

    hipMemsetAsync(stats, 0, 512, stream);
    k_prep  <<<B * 128, 256, 0, stream>>>(x, Xh, Xm, Xl, nsq);
    k_knn   <<<B * 64 * KSEG, 256, 0, stream>>>(Xh, Xm, Xl, nsq, partd, parti);
    k_merge <<<(B * N) / 256, 256, 0, stream>>>(partd, parti, nn);
    k_ag    <<<B * 128, 256, 0, stream>>>(x, W, A, G);
    k_stats <<<B * 128, 256, 0, stream>>>(A, G, nn, ymax, ymin, stats);
    k_final <<<B * 128, 256, 0, stream>>>(ymax, ymin, stats, gamma, beta, out);
}